// Round 6
// baseline (66.224 us; speedup 1.0000x reference)
//
#include <hip/hip_runtime.h>

// DIAGNOSTIC ROUND: exact R1 kernel body executed NPASS=3 times per dispatch
// (idempotent re-writes; asm memory clobber prevents cross-pass load CSE).
// Purpose: push our dispatch above the harness's 39us fill kernels so it
// finally appears in the rocprof top-5 and we get FETCH/WRITE/VALUBusy/Occ
// for our own kernel. dur_us this round is intentionally ~3x and throwaway.

#define HH 56
#define WW 56
#define LL 3136
#define CW 32
#define SHARE 8
#define CC 256
#define NN 8
#define NPASS 3

__global__ __launch_bounds__(256) void agg_kernel(const float* __restrict__ in,
                                                  const float* __restrict__ wt,
                                                  float* __restrict__ out) {
    const int l = blockIdx.x * 256 + threadIdx.x;
    const int g = blockIdx.y;   // weight-channel group, 0..31
    const int n = blockIdx.z;   // batch, 0..7
    if (l >= LL) return;
    const int h = l / WW;
    const int w = l - h * WW;

    // Tap offsets + validity (zero padding of 1). Pure index math, hoisted.
    int off[9];
    bool val[9];
#pragma unroll
    for (int kk = 0; kk < 9; ++kk) {
        const int hh = h + kk / 3 - 1;
        const int ww = w + kk % 3 - 1;
        val[kk] = ((unsigned)hh < (unsigned)HH) && ((unsigned)ww < (unsigned)WW);
        off[kk] = hh * WW + ww;
    }

    const float* wp = wt + (((size_t)n * CW + g) * 9) * LL + l;
    const int c0 = g * SHARE;
    const float* ip = in + ((size_t)n * CC + c0) * LL;
    float* op = out + ((size_t)n * CC + c0) * LL;

#pragma unroll 1
    for (int pass = 0; pass < NPASS; ++pass) {
        asm volatile("" ::: "memory");   // force real reloads each pass
        float w9[9];
#pragma unroll
        for (int kk = 0; kk < 9; ++kk) w9[kk] = wp[(size_t)kk * LL];
#pragma unroll
        for (int s = 0; s < SHARE; ++s) {
            float acc = 0.f;
#pragma unroll
            for (int kk = 0; kk < 9; ++kk) {
                const float v = val[kk] ? ip[(size_t)s * LL + off[kk]] : 0.f;
                acc = fmaf(v, w9[kk], acc);
            }
            op[(size_t)s * LL + l] = acc;
        }
    }
}

extern "C" void kernel_launch(void* const* d_in, const int* in_sizes, int n_in,
                              void* d_out, int out_size, void* d_ws, size_t ws_size,
                              hipStream_t stream) {
    const float* in = (const float*)d_in[0];
    const float* wt = (const float*)d_in[1];
    float* out = (float*)d_out;
    dim3 grid((LL + 255) / 256, CW, NN);
    agg_kernel<<<grid, 256, 0, stream>>>(in, wt, out);
}

// Round 7
// 40.294 us; speedup vs baseline: 1.6435x; 1.6435x over previous
//
#include <hip/hip_runtime.h>

// Aggregation (SAN-style): out[n,c,l] = sum_kk input_pad[n,c,tap(l,kk)] * weight[n, c/8, kk, l]
// N=8, C=256, Cw=32, share=8, K=3, H=W=56, L=3136. All fp32.
//
// R7: latency-oriented light threads. One thread = 4 outputs (one aligned quad)
// of ONE channel. 19 independent loads -> single vmcnt wait -> 36 FMA -> store.
// 1.6M threads / 25088 waves for deep latency hiding. Weight float4s are
// re-read by the 8 channels of a group -> L1/L2 hits (L3-resident workload).

#define HH 56
#define WW 56
#define LL 3136
#define CC 256
#define NN 8
#define QPP 784                      // quads per plane (56*14)
#define TOTAL (NN * CC * QPP)        // 1,605,632 threads = 6272 blocks * 256

__global__ __launch_bounds__(256) void agg_kernel(const float* __restrict__ in,
                                                  const float* __restrict__ wt,
                                                  float* __restrict__ out) {
    const unsigned idx = blockIdx.x * 256u + threadIdx.x;   // TOTAL exact
    const unsigned q  = idx % QPP;
    const unsigned nc = idx / QPP;
    const unsigned c  = nc & 255u;
    const unsigned n  = nc >> 8;
    const unsigned g  = c >> 3;
    const unsigned h  = q / 14u;
    const unsigned w  = (q - h * 14u) * 4u;
    const unsigned l  = h * WW + w;          // 16B-aligned

    // 9 weight float4 loads (independent)
    const float* wp = wt + (((size_t)n * 32u + g) * 9u) * LL + l;
    float4 wv[9];
#pragma unroll
    for (int kk = 0; kk < 9; ++kk) wv[kk] = *(const float4*)(wp + (size_t)kk * LL);

    // 3 input rows x (aligned float4 + 2 edge scalars), all independent
    const float* ip = in + ((size_t)n * CC + c) * LL;
    const bool wl = (w > 0), wr = (w < 52u);
    float4 cv[3];
    float  le[3], re[3];
#pragma unroll
    for (int r = 0; r < 3; ++r) {
        const int gr = (int)h + r - 1;
        const bool rv = ((unsigned)gr < HH);
        const float* qp = ip + (size_t)gr * WW + w;
        cv[r] = rv ? *(const float4*)qp : make_float4(0.f, 0.f, 0.f, 0.f);
        le[r] = (rv && wl) ? qp[-1] : 0.f;
        re[r] = (rv && wr) ? qp[4]  : 0.f;
    }

    float a0 = 0.f, a1 = 0.f, a2 = 0.f, a3 = 0.f;
#pragma unroll
    for (int r = 0; r < 3; ++r) {
        const float4 wa = wv[3 * r + 0];   // dw = -1
        const float4 wb = wv[3 * r + 1];   // dw =  0
        const float4 wc = wv[3 * r + 2];   // dw = +1
        const float4 c4 = cv[r];
        a0 = fmaf(le[r], wa.x, a0);
        a1 = fmaf(c4.x,  wa.y, a1);
        a2 = fmaf(c4.y,  wa.z, a2);
        a3 = fmaf(c4.z,  wa.w, a3);
        a0 = fmaf(c4.x,  wb.x, a0);
        a1 = fmaf(c4.y,  wb.y, a1);
        a2 = fmaf(c4.z,  wb.z, a2);
        a3 = fmaf(c4.w,  wb.w, a3);
        a0 = fmaf(c4.y,  wc.x, a0);
        a1 = fmaf(c4.z,  wc.y, a1);
        a2 = fmaf(c4.w,  wc.z, a2);
        a3 = fmaf(re[r], wc.w, a3);
    }

    float* op = out + ((size_t)n * CC + c) * LL + l;
    *(float4*)op = make_float4(a0, a1, a2, a3);
}

extern "C" void kernel_launch(void* const* d_in, const int* in_sizes, int n_in,
                              void* d_out, int out_size, void* d_ws, size_t ws_size,
                              hipStream_t stream) {
    const float* in = (const float*)d_in[0];
    const float* wt = (const float*)d_in[1];
    float* out = (float*)d_out;
    agg_kernel<<<dim3(TOTAL / 256), dim3(256), 0, stream>>>(in, wt, out);
}

// Round 8
// 20.769 us; speedup vs baseline: 3.1887x; 1.9402x over previous
//
#include <hip/hip_runtime.h>

// Aggregation (SAN-style): out[n,c,l] = sum_kk input_pad[n,c,tap(l,kk)] * weight[n, c/8, kk, l]
// N=8, C=256, Cw=32, share=8, K=3, H=W=56, L=3136. All fp32.
//
// R8: register-shift stencil. One wave = one image row (lanes = w, 56 active).
// Per channel: 3 coalesced row loads (h-1,h,h+1); horizontal taps via
// __shfl_up/__shfl_down (LDS-permute pipe) instead of L1 re-reads; w-edge
// zero-padding via lane masks (no edge loads, no divergence, no OOB).
// VMEM 89 -> 41 instrs/wave; L1 line-touches ~2.6x lower than R1.
// Grid: 8*32*14 = 3584 blocks = exactly 14/CU; block = 4 consecutive rows.

#define HH 56
#define WW 56
#define LL 3136
#define CW 32
#define CC 256
#define NN 8

__global__ __launch_bounds__(256) void agg_kernel(const float* __restrict__ in,
                                                  const float* __restrict__ wt,
                                                  float* __restrict__ out) {
    const unsigned t    = threadIdx.x;
    const unsigned wid  = t >> 6;            // wave 0..3 -> row in band
    const unsigned lane = t & 63u;           // w position (56 active)
    const unsigned b    = blockIdx.x;
    const unsigned hb   = b % 14u;           // 4-row band index
    const unsigned ng   = b / 14u;
    const unsigned g    = ng & 31u;
    const unsigned n    = ng >> 5;
    const unsigned h    = hb * 4u + wid;     // 0..55 (uniform per wave)
    const unsigned w    = lane;
    const unsigned wcl  = (w < 55u) ? w : 55u;   // clamp lanes 56..63 (no OOB)
    const unsigned l    = h * WW + wcl;

    // 9 per-location weights, one scalar per lane (coalesced, 56x4B per tap)
    const float* wp = wt + (((size_t)n * CW + g) * 9u) * LL + l;
    float w9[9];
#pragma unroll
    for (int k = 0; k < 9; ++k) w9[k] = wp[(size_t)k * LL];

    const bool up = (h > 0), dn = (h < HH - 1);     // wave-uniform branches
    const bool wz = (w == 0), we = (w >= 55u);      // lane masks for pad
    const float* ip = in  + ((size_t)n * CC + g * 8u) * LL + l;
    float*       op = out + ((size_t)n * CC + g * 8u) * LL + l;

    // Hoist all 24 row loads (8 ch x 3 rows), fully independent -> one wait.
    float cm[8], cc[8], cp[8];
#pragma unroll
    for (int ch = 0; ch < 8; ++ch) {
        const float* p = ip + (size_t)ch * LL;
        cm[ch] = up ? p[-(int)WW] : 0.f;
        cc[ch] = p[0];
        cp[ch] = dn ? p[WW] : 0.f;
    }

#pragma unroll
    for (int ch = 0; ch < 8; ++ch) {
        float acc = 0.f;
        {   // row h-1: taps kk 0,1,2
            float lf = __shfl_up(cm[ch], 1);
            float rt = __shfl_down(cm[ch], 1);
            lf = wz ? 0.f : lf;  rt = we ? 0.f : rt;
            acc = fmaf(lf, w9[0], acc);
            acc = fmaf(cm[ch], w9[1], acc);
            acc = fmaf(rt, w9[2], acc);
        }
        {   // row h: taps kk 3,4,5
            float lf = __shfl_up(cc[ch], 1);
            float rt = __shfl_down(cc[ch], 1);
            lf = wz ? 0.f : lf;  rt = we ? 0.f : rt;
            acc = fmaf(lf, w9[3], acc);
            acc = fmaf(cc[ch], w9[4], acc);
            acc = fmaf(rt, w9[5], acc);
        }
        {   // row h+1: taps kk 6,7,8
            float lf = __shfl_up(cp[ch], 1);
            float rt = __shfl_down(cp[ch], 1);
            lf = wz ? 0.f : lf;  rt = we ? 0.f : rt;
            acc = fmaf(lf, w9[6], acc);
            acc = fmaf(cp[ch], w9[7], acc);
            acc = fmaf(rt, w9[8], acc);
        }
        if (w < 56u) op[(size_t)ch * LL] = acc;
    }
}

extern "C" void kernel_launch(void* const* d_in, const int* in_sizes, int n_in,
                              void* d_out, int out_size, void* d_ws, size_t ws_size,
                              hipStream_t stream) {
    const float* in = (const float*)d_in[0];
    const float* wt = (const float*)d_in[1];
    float* out = (float*)d_out;
    agg_kernel<<<dim3(NN * CW * 14), dim3(256), 0, stream>>>(in, wt, out);
}

// Round 9
// 20.214 us; speedup vs baseline: 3.2761x; 1.0274x over previous
//
#include <hip/hip_runtime.h>

// Aggregation (SAN-style): out[n,c,l] = sum_kk input_pad[n,c,tap(l,kk)] * weight[n, c/8, kk, l]
// N=8, C=256, Cw=32, share=8, K=3, H=W=56, L=3136. All fp32.
//
// R9: minimum-VMEM structure. Wave = 56 active lanes = 4 rows x 14 quads
// (quad = 4 consecutive w, float4-aligned) of ONE channel. Block = 8 waves =
// the 8 share-channels of one (n, g, 4-row band) -> weight float4s loaded by
// wave 0 hit L1 for waves 1..7. Vertical taps via shfl +/-14 (rows live in
// neighbor lanes), horizontal taps via shfl +/-1 of quad edge elements.
// Per wave: 9 wt float4 + 1 center float4 + 2 masked halo float4 loads,
// 1 float4 store. 13 VMEM/wave vs R8's 49.

#define HH 56
#define WW 56
#define LL 3136
#define CW 32
#define CC 256
#define NN 8

__device__ __forceinline__ float4 shfl_up4(float4 v, int d) {
    return make_float4(__shfl_up(v.x, d), __shfl_up(v.y, d),
                       __shfl_up(v.z, d), __shfl_up(v.w, d));
}
__device__ __forceinline__ float4 shfl_down4(float4 v, int d) {
    return make_float4(__shfl_down(v.x, d), __shfl_down(v.y, d),
                       __shfl_down(v.z, d), __shfl_down(v.w, d));
}

__global__ __launch_bounds__(512) void agg_kernel(const float* __restrict__ in,
                                                  const float* __restrict__ wt,
                                                  float* __restrict__ out) {
    const unsigned t    = threadIdx.x;
    const unsigned wid  = t >> 6;              // 0..7 -> channel within group
    const unsigned lane = t & 63u;
    const unsigned b    = blockIdx.x;
    const unsigned band = b % 14u;             // 4-row band
    const unsigned ng   = b / 14u;
    const unsigned g    = ng & 31u;
    const unsigned n    = ng >> 5;

    const unsigned rq = (lane < 56u) ? lane : 55u;  // clamp tail lanes
    const unsigned r  = rq / 14u;              // row in band, 0..3
    const unsigned q  = rq - r * 14u;          // quad in row, 0..13
    const unsigned h  = band * 4u + r;         // global row 0..55
    const unsigned w4 = q * 4u;
    const unsigned l  = h * WW + w4;           // 16B-aligned

    // ---- 9 weight float4 loads (block-shared addresses -> L1 reuse) ----
    const float* wp = wt + (((size_t)n * CW + g) * 9u) * LL + l;
    float4 wv[9];
#pragma unroll
    for (int k = 0; k < 9; ++k) wv[k] = *(const float4*)(wp + (size_t)k * LL);

    // ---- input: own center row + masked band-halo rows ----
    const unsigned c = g * 8u + wid;
    const float* ip = in + ((size_t)n * CC + c) * LL;
    const float4 c4 = *(const float4*)(ip + l);
    float4 hm = make_float4(0.f, 0.f, 0.f, 0.f);
    float4 hp = make_float4(0.f, 0.f, 0.f, 0.f);
    if (r == 0u && h > 0u)       hm = *(const float4*)(ip + l - WW);
    if (r == 3u && h < HH - 1u)  hp = *(const float4*)(ip + l + WW);

    // ---- vertical windows: row h-1 / h+1 from neighbor lanes or halo ----
    const float4 sm = shfl_up4(c4, 14);
    const float4 sp = shfl_down4(c4, 14);
    const float4 rm = (r == 0u) ? hm : sm;
    const float4 rp = (r == 3u) ? hp : sp;

    // ---- horizontal edges: prev quad's .w / next quad's .x ----
    const bool qz = (q == 0u), qe = (q == 13u);
    float lm = __shfl_up(rm.w, 1), lc = __shfl_up(c4.w, 1), lp = __shfl_up(rp.w, 1);
    float em = __shfl_down(rm.x, 1), ec = __shfl_down(c4.x, 1), ep = __shfl_down(rp.x, 1);
    if (qz) { lm = 0.f; lc = 0.f; lp = 0.f; }
    if (qe) { em = 0.f; ec = 0.f; ep = 0.f; }

    // ---- 9-tap FMA per element ----
    float4 a = make_float4(0.f, 0.f, 0.f, 0.f);
    // dr = -1 (taps 0,1,2)
    a.x = fmaf(lm,   wv[0].x, a.x); a.y = fmaf(rm.x, wv[0].y, a.y);
    a.z = fmaf(rm.y, wv[0].z, a.z); a.w = fmaf(rm.z, wv[0].w, a.w);
    a.x = fmaf(rm.x, wv[1].x, a.x); a.y = fmaf(rm.y, wv[1].y, a.y);
    a.z = fmaf(rm.z, wv[1].z, a.z); a.w = fmaf(rm.w, wv[1].w, a.w);
    a.x = fmaf(rm.y, wv[2].x, a.x); a.y = fmaf(rm.z, wv[2].y, a.y);
    a.z = fmaf(rm.w, wv[2].z, a.z); a.w = fmaf(em,   wv[2].w, a.w);
    // dr = 0 (taps 3,4,5)
    a.x = fmaf(lc,   wv[3].x, a.x); a.y = fmaf(c4.x, wv[3].y, a.y);
    a.z = fmaf(c4.y, wv[3].z, a.z); a.w = fmaf(c4.z, wv[3].w, a.w);
    a.x = fmaf(c4.x, wv[4].x, a.x); a.y = fmaf(c4.y, wv[4].y, a.y);
    a.z = fmaf(c4.z, wv[4].z, a.z); a.w = fmaf(c4.w, wv[4].w, a.w);
    a.x = fmaf(c4.y, wv[5].x, a.x); a.y = fmaf(c4.z, wv[5].y, a.y);
    a.z = fmaf(c4.w, wv[5].z, a.z); a.w = fmaf(ec,   wv[5].w, a.w);
    // dr = +1 (taps 6,7,8)
    a.x = fmaf(lp,   wv[6].x, a.x); a.y = fmaf(rp.x, wv[6].y, a.y);
    a.z = fmaf(rp.y, wv[6].z, a.z); a.w = fmaf(rp.z, wv[6].w, a.w);
    a.x = fmaf(rp.x, wv[7].x, a.x); a.y = fmaf(rp.y, wv[7].y, a.y);
    a.z = fmaf(rp.z, wv[7].z, a.z); a.w = fmaf(rp.w, wv[7].w, a.w);
    a.x = fmaf(rp.y, wv[8].x, a.x); a.y = fmaf(rp.z, wv[8].y, a.y);
    a.z = fmaf(rp.w, wv[8].z, a.z); a.w = fmaf(ep,   wv[8].w, a.w);

    if (lane < 56u) {
        float* op = out + ((size_t)n * CC + c) * LL + l;
        *(float4*)op = a;
    }
}

extern "C" void kernel_launch(void* const* d_in, const int* in_sizes, int n_in,
                              void* d_out, int out_size, void* d_ws, size_t ws_size,
                              hipStream_t stream) {
    const float* in = (const float*)d_in[0];
    const float* wt = (const float*)d_in[1];
    float* out = (float*)d_out;
    agg_kernel<<<dim3(NN * CW * 14), dim3(512), 0, stream>>>(in, wt, out);
}

// Round 10
// 19.029 us; speedup vs baseline: 3.4802x; 1.0623x over previous
//
#include <hip/hip_runtime.h>

// Aggregation (SAN-style): out[n,c,l] = sum_kk input_pad[n,c,tap(l,kk)] * weight[n, c/8, kk, l]
// N=8, C=256, Cw=32, share=8, K=3, H=W=56, L=3136. All fp32.
//
// R10 = R9 + XCD-aware block swizzle (single change). Work-id decoded as
// b = (phys%8)*448 + phys/8 so all 14 bands of each (n,g) — and 32 whole
// (n,g) slices — run on ONE XCD: band-halo row re-reads hit that XCD's L2
// instead of crossing the fabric to L3. Bijective: 3584 = 8*448 exactly.

#define HH 56
#define WW 56
#define LL 3136
#define CW 32
#define CC 256
#define NN 8
#define NWG (NN * CW * 14)   // 3584 blocks
#define CHUNK (NWG / 8)      // 448 per XCD

__device__ __forceinline__ float4 shfl_up4(float4 v, int d) {
    return make_float4(__shfl_up(v.x, d), __shfl_up(v.y, d),
                       __shfl_up(v.z, d), __shfl_up(v.w, d));
}
__device__ __forceinline__ float4 shfl_down4(float4 v, int d) {
    return make_float4(__shfl_down(v.x, d), __shfl_down(v.y, d),
                       __shfl_down(v.z, d), __shfl_down(v.w, d));
}

__global__ __launch_bounds__(512) void agg_kernel(const float* __restrict__ in,
                                                  const float* __restrict__ wt,
                                                  float* __restrict__ out) {
    const unsigned t    = threadIdx.x;
    const unsigned wid  = t >> 6;              // 0..7 -> channel within group
    const unsigned lane = t & 63u;
    // XCD swizzle: physical blocks round-robin XCDs; make work-ids contiguous per XCD.
    const unsigned bp   = blockIdx.x;
    const unsigned b    = (bp & 7u) * CHUNK + (bp >> 3);
    const unsigned band = b % 14u;             // 4-row band
    const unsigned ng   = b / 14u;
    const unsigned g    = ng & 31u;
    const unsigned n    = ng >> 5;

    const unsigned rq = (lane < 56u) ? lane : 55u;  // clamp tail lanes
    const unsigned r  = rq / 14u;              // row in band, 0..3
    const unsigned q  = rq - r * 14u;          // quad in row, 0..13
    const unsigned h  = band * 4u + r;         // global row 0..55
    const unsigned w4 = q * 4u;
    const unsigned l  = h * WW + w4;           // 16B-aligned

    // ---- 9 weight float4 loads (block-shared addresses -> L1 reuse) ----
    const float* wp = wt + (((size_t)n * CW + g) * 9u) * LL + l;
    float4 wv[9];
#pragma unroll
    for (int k = 0; k < 9; ++k) wv[k] = *(const float4*)(wp + (size_t)k * LL);

    // ---- input: own center row + masked band-halo rows ----
    const unsigned c = g * 8u + wid;
    const float* ip = in + ((size_t)n * CC + c) * LL;
    const float4 c4 = *(const float4*)(ip + l);
    float4 hm = make_float4(0.f, 0.f, 0.f, 0.f);
    float4 hp = make_float4(0.f, 0.f, 0.f, 0.f);
    if (r == 0u && h > 0u)       hm = *(const float4*)(ip + l - WW);
    if (r == 3u && h < HH - 1u)  hp = *(const float4*)(ip + l + WW);

    // ---- vertical windows: row h-1 / h+1 from neighbor lanes or halo ----
    const float4 sm = shfl_up4(c4, 14);
    const float4 sp = shfl_down4(c4, 14);
    const float4 rm = (r == 0u) ? hm : sm;
    const float4 rp = (r == 3u) ? hp : sp;

    // ---- horizontal edges: prev quad's .w / next quad's .x ----
    const bool qz = (q == 0u), qe = (q == 13u);
    float lm = __shfl_up(rm.w, 1), lc = __shfl_up(c4.w, 1), lp = __shfl_up(rp.w, 1);
    float em = __shfl_down(rm.x, 1), ec = __shfl_down(c4.x, 1), ep = __shfl_down(rp.x, 1);
    if (qz) { lm = 0.f; lc = 0.f; lp = 0.f; }
    if (qe) { em = 0.f; ec = 0.f; ep = 0.f; }

    // ---- 9-tap FMA per element ----
    float4 a = make_float4(0.f, 0.f, 0.f, 0.f);
    // dr = -1 (taps 0,1,2)
    a.x = fmaf(lm,   wv[0].x, a.x); a.y = fmaf(rm.x, wv[0].y, a.y);
    a.z = fmaf(rm.y, wv[0].z, a.z); a.w = fmaf(rm.z, wv[0].w, a.w);
    a.x = fmaf(rm.x, wv[1].x, a.x); a.y = fmaf(rm.y, wv[1].y, a.y);
    a.z = fmaf(rm.z, wv[1].z, a.z); a.w = fmaf(rm.w, wv[1].w, a.w);
    a.x = fmaf(rm.y, wv[2].x, a.x); a.y = fmaf(rm.z, wv[2].y, a.y);
    a.z = fmaf(rm.w, wv[2].z, a.z); a.w = fmaf(em,   wv[2].w, a.w);
    // dr = 0 (taps 3,4,5)
    a.x = fmaf(lc,   wv[3].x, a.x); a.y = fmaf(c4.x, wv[3].y, a.y);
    a.z = fmaf(c4.y, wv[3].z, a.z); a.w = fmaf(c4.z, wv[3].w, a.w);
    a.x = fmaf(c4.x, wv[4].x, a.x); a.y = fmaf(c4.y, wv[4].y, a.y);
    a.z = fmaf(c4.z, wv[4].z, a.z); a.w = fmaf(c4.w, wv[4].w, a.w);
    a.x = fmaf(c4.y, wv[5].x, a.x); a.y = fmaf(c4.z, wv[5].y, a.y);
    a.z = fmaf(c4.w, wv[5].z, a.z); a.w = fmaf(ec,   wv[5].w, a.w);
    // dr = +1 (taps 6,7,8)
    a.x = fmaf(lp,   wv[6].x, a.x); a.y = fmaf(rp.x, wv[6].y, a.y);
    a.z = fmaf(rp.y, wv[6].z, a.z); a.w = fmaf(rp.z, wv[6].w, a.w);
    a.x = fmaf(rp.x, wv[7].x, a.x); a.y = fmaf(rp.y, wv[7].y, a.y);
    a.z = fmaf(rp.z, wv[7].z, a.z); a.w = fmaf(rp.w, wv[7].w, a.w);
    a.x = fmaf(rp.y, wv[8].x, a.x); a.y = fmaf(rp.z, wv[8].y, a.y);
    a.z = fmaf(rp.w, wv[8].z, a.z); a.w = fmaf(ep,   wv[8].w, a.w);

    if (lane < 56u) {
        float* op = out + ((size_t)n * CC + c) * LL + l;
        *(float4*)op = a;
    }
}

extern "C" void kernel_launch(void* const* d_in, const int* in_sizes, int n_in,
                              void* d_out, int out_size, void* d_ws, size_t ws_size,
                              hipStream_t stream) {
    const float* in = (const float*)d_in[0];
    const float* wt = (const float*)d_in[1];
    float* out = (float*)d_out;
    agg_kernel<<<dim3(NWG), dim3(512), 0, stream>>>(in, wt, out);
}